// Round 15
// baseline (92.041 us; speedup 1.0000x reference)
//
#include <hip/hip_runtime.h>
#include <cstdint>

#define NB 32
#define NROIS 8192
#define NGT 128
#define NALL (NROIS + NGT)   // 8320
#define NSAMP 512
#define KPOS 128
#define KNEG 384
#define BCAP 1024
#define TS 1024              // k_select threads (16 waves)
#define CH 9                 // ceil(NALL/TS)

// ---------------- Kernel 1a: negative screen + compaction ----------------
// 128 thr/block, 1 roi/thread, grid (65,32). Tracks ONLY the max over gts of
// t_j = 3*inter_j - ab_j (no argmax state, no cndmask): roi can have
// iou >= 0.5 only if 3I >= S - eps  <=>  max_j t_j >= aar - eps. Slack 16
// (px^2) dwarfs total FP error (<~0.1) -> every reference-positive roi is
// flagged; unflagged rois are provably negative (code=1) and their col is
// NEVER consumed downstream (reference zeroes encode/class for background).
// Flagged rois are appended to a per-batch list for exact re-scan. Masked
// [-1]*4 boxes -> full reference slow path for the block (flags nothing).
__global__ __launch_bounds__(128) void k_match(
    const float* __restrict__ rois,   // B,NROIS,4
    const float* __restrict__ gt,     // B,NGT,4
    const float* __restrict__ noise,  // B,NALL,2
    int* __restrict__ mword,          // B*NALL : col | code<<7 | bin<<9
    int* __restrict__ flcnt,          // B counters (pre-zeroed)
    int* __restrict__ fllist)         // B,NALL flagged roi indices
{
  __shared__ float4 sg[NGT];
  __shared__ float sab[NGT];
  __shared__ unsigned long long smask[2];

  const int b = blockIdx.y;
  const int tid = threadIdx.x;
  const float4* gt4 = reinterpret_cast<const float4*>(gt) + (size_t)b * NGT;
  const float4* rois4 = reinterpret_cast<const float4*>(rois) + (size_t)b * NROIS;

  // prologue: stage gt boxes + areas + mask ballot (tid covers all 128 gts)
  float4 g0 = gt4[tid];
  sg[tid] = g0;
  sab[tid] = (g0.z - g0.x) * (g0.w - g0.y);
  const bool mflag = (g0.x == -1.0f) && (g0.y == -1.0f) && (g0.z == -1.0f) && (g0.w == -1.0f);
  const unsigned long long mb = __ballot(mflag);
  if ((tid & 63) == 0) smask[tid >> 6] = mb;
  __syncthreads();
  const bool anymask = (smask[0] | smask[1]) != 0ULL;

  const int i = blockIdx.x * 128 + tid;   // 65*128 == NALL exactly
  float4 A = (blockIdx.x < 64) ? rois4[i] : sg[tid];
  const float aar = (A.z - A.x) * (A.w - A.y);
  const bool ma = (A.x == -1.0f) && (A.y == -1.0f) && (A.z == -1.0f) && (A.w == -1.0f);

  if (!anymask && __ballot(ma) == 0ULL) {
    // ---- fast screen: max of t = 3*inter - ab, imm-offset LDS reads ----
    float m0 = -3.0e38f, m1 = -3.0e38f;
    for (int jo = 0; jo < 64; jo += 32) {
      const float4* p0 = &sg[jo];
      const float4* p1 = &sg[jo + 64];
      const float* a0 = &sab[jo];
      const float* a1 = &sab[jo + 64];
      #pragma unroll
      for (int jj = 0; jj < 32; ++jj) {
        {
          const float4 g = p0[jj];
          float iy = fmaxf(fminf(A.z, g.z) - fmaxf(A.x, g.x), 0.0f);
          float ix = fmaxf(fminf(A.w, g.w) - fmaxf(A.y, g.y), 0.0f);
          float inter = iy * ix;
          m0 = fmaxf(m0, fmaf(3.0f, inter, -a0[jj]));
        }
        {
          const float4 g = p1[jj];
          float iy = fmaxf(fminf(A.z, g.z) - fmaxf(A.x, g.x), 0.0f);
          float ix = fmaxf(fminf(A.w, g.w) - fmaxf(A.y, g.y), 0.0f);
          float inter = iy * ix;
          m1 = fmaxf(m1, fmaf(3.0f, inter, -a1[jj]));
        }
      }
    }
    const bool flagged = fmaxf(m0, m1) >= (aar - 16.0f);
    if (flagged) {
      const int p = atomicAdd(&flcnt[b], 1);
      fllist[(size_t)b * NALL + p] = i;
    } else {
      // provably negative: code=1, col unused (0)
      float2 nz = reinterpret_cast<const float2*>(noise)[(size_t)b * NALL + i];
      int bin = (int)(nz.y * 1024.0f);
      bin = bin < 0 ? 0 : (bin > 1023 ? 1023 : bin);
      mword[(size_t)b * NALL + i] = (1 << 7) | (bin << 9);
    }
  } else {
    // ---- slow path (masked boxes; never taken for this data) ----
    #pragma clang fp contract(off)
    float bb = -3.0e38f;
    int cc = 0;
    for (int j = 0; j < NGT; ++j) {
      float4 gg = sg[j];
      const bool mj = (gg.x == -1.0f) && (gg.y == -1.0f) && (gg.z == -1.0f) && (gg.w == -1.0f);
      float iy = fmaxf(fminf(A.z, gg.z) - fmaxf(A.x, gg.x), 0.0f);
      float ix = fmaxf(fminf(A.w, gg.w) - fmaxf(A.y, gg.y), 0.0f);
      float inter = iy * ix;
      float uni = (aar + sab[j]) - inter;
      float iou = inter / fmaxf(uni, 1e-8f);
      if (ma || mj) iou = -1.0f;
      if (iou > bb) { bb = iou; cc = j; }   // ascending strict > = first-max
    }
    int code = (bb >= 0.5f) ? 3 : ((bb >= 0.0f) ? 1 : 0);
    float2 nz = reinterpret_cast<const float2*>(noise)[(size_t)b * NALL + i];
    float v = (code == 3) ? nz.x : nz.y;
    int bin = (int)(v * 1024.0f);
    bin = bin < 0 ? 0 : (bin > 1023 ? 1023 : bin);
    mword[(size_t)b * NALL + i] = cc | (code << 7) | (bin << 9);
  }
}

// ---------------- Kernel 1b: exact dense re-scan of flagged rois -------------
// grid (33, NB) x 256thr; block handles 256 consecutive flagged entries of
// its batch (capacity 8448 >= NALL; excess blocks exit before staging).
// R9-validated exact path: cross-mul argmax (iou_j > iou_b <=> inter_j*uc_b >
// inter_b*uc_j, uc=max(uni,1e-8)>0), 4 ascending chains, strict >, lower
// chain wins ties; ONE contract-off IEEE div on the winner for the exact
// >=0.5 / >=0.0 code. Flagged entries only come from maskless blocks.
__global__ __launch_bounds__(256) void k_match2(
    const float* __restrict__ rois,
    const float* __restrict__ gt,
    const float* __restrict__ noise,
    const int* __restrict__ flcnt,
    const int* __restrict__ fllist,
    int* __restrict__ mword)
{
  const int b = blockIdx.y;
  const int cnt = flcnt[b];
  const int base = blockIdx.x * 256 + threadIdx.x;
  if (blockIdx.x * 256 >= cnt) return;

  __shared__ float4 sg[NGT];
  const float4* gt4 = reinterpret_cast<const float4*>(gt) + (size_t)b * NGT;
  if (threadIdx.x < NGT) sg[threadIdx.x] = gt4[threadIdx.x];
  __syncthreads();

  if (base >= cnt) return;
  const int i = fllist[(size_t)b * NALL + base];
  const float4* rois4 = reinterpret_cast<const float4*>(rois) + (size_t)b * NROIS;
  float4 A = (i < NROIS) ? rois4[i] : sg[i - NROIS];
  const float aar = (A.z - A.x) * (A.w - A.y);

  float bi[4], bu[4];
  int bc[4];
  #pragma unroll
  for (int c = 0; c < 4; ++c) { bi[c] = 0.0f; bu[c] = 1.0f; bc[c] = c * 32; }

  #pragma unroll 8
  for (int jj = 0; jj < 32; ++jj) {
    #pragma unroll
    for (int c = 0; c < 4; ++c) {
      const int j = c * 32 + jj;
      const float4 g = sg[j];
      const float ab = (g.z - g.x) * (g.w - g.y);
      float iy = fmaxf(fminf(A.z, g.z) - fmaxf(A.x, g.x), 0.0f);
      float ix = fmaxf(fminf(A.w, g.w) - fmaxf(A.y, g.y), 0.0f);
      float inter = iy * ix;
      float uc = fmaxf((aar + ab) - inter, 1e-8f);
      const bool win = (inter * bu[c]) > (bi[c] * uc);
      bi[c] = win ? inter : bi[c];
      bu[c] = win ? uc : bu[c];
      bc[c] = win ? j : bc[c];
    }
  }
  float qi = bi[0], qu = bu[0];
  int cc = bc[0];
  #pragma unroll
  for (int c = 1; c < 4; ++c) {
    const bool win = (bi[c] * qu) > (qi * bu[c]);
    qi = win ? bi[c] : qi; qu = win ? bu[c] : qu; cc = win ? bc[c] : cc;
  }

  int code;
  {
    #pragma clang fp contract(off)
    const float4 g = sg[cc];
    float iy = fmaxf(fminf(A.z, g.z) - fmaxf(A.x, g.x), 0.0f);
    float ix = fmaxf(fminf(A.w, g.w) - fmaxf(A.y, g.y), 0.0f);
    float inter = iy * ix;
    float ab = (g.z - g.x) * (g.w - g.y);
    float uni = (aar + ab) - inter;
    float bb = inter / fmaxf(uni, 1e-8f);   // IEEE-exact, matches reference max
    code = (bb >= 0.5f) ? 3 : ((bb >= 0.0f) ? 1 : 0);
  }
  float2 nz = reinterpret_cast<const float2*>(noise)[(size_t)b * NALL + i];
  float v = (code == 3) ? nz.x : nz.y;
  int bin = (int)(v * 1024.0f);
  bin = bin < 0 ? 0 : (bin > 1023 ? 1023 : bin);
  mword[(size_t)b * NALL + i] = cc | (code << 7) | (bin << 9);
}

// ---------------- shfl-based block inclusive scan (TS=1024, 16 waves) -------
__device__ __forceinline__ int block_incl_scan(int v, int tid, int* wsum) {
  __syncthreads();  // protect wsum reuse across consecutive calls
  int s = v;
  #pragma unroll
  for (int off = 1; off < 64; off <<= 1) {
    int u = __shfl_up(s, off);
    if ((tid & 63) >= off) s += u;
  }
  const int wid = tid >> 6;
  if ((tid & 63) == 63) wsum[wid] = s;
  __syncthreads();
  if (wid == 0) {
    const int lane = tid & 63;
    int w = (lane < (TS >> 6)) ? wsum[lane] : 0;
    #pragma unroll
    for (int off = 1; off < (TS >> 6); off <<= 1) {
      int u = __shfl_up(w, off);
      if (lane >= off) w += u;
    }
    if (lane < (TS >> 6)) wsum[lane] = w;
  }
  __syncthreads();
  return s + (wid ? wsum[wid - 1] : 0);
}

// ---------------- Kernel 2: balanced sampling + ordering + gather ------------
__global__ __launch_bounds__(TS) void k_select(
    const int* __restrict__ mword,
    const float* __restrict__ noise,  // B,NALL,2
    const float* __restrict__ rois,
    const float* __restrict__ gt,
    const float* __restrict__ gtcls,  // B,NGT,1
    float* __restrict__ out)
{
  #pragma clang fp contract(off)
  const int b = blockIdx.x;
  const int tid = threadIdx.x;

  __shared__ int hist[1024];            // packed pos|neg<<16
  __shared__ int wsum[TS >> 6];
  __shared__ int s_total;               // packed totals
  __shared__ float bval[2][BCAP];
  __shared__ int bidx_[2][BCAP];
  __shared__ int bcnt[2];
  __shared__ int s_bstar[2], s_need[2];
  __shared__ unsigned char ind[NALL];
  __shared__ unsigned short sorder[NSAMP];

  int ew[CH];     // packed word; bit7 set => candidate

  hist[tid] = 0;
  if (tid < 2) bcnt[tid] = 0;

  // ---- pass 1: one int load per element; histogram + ind init ----
  #pragma unroll
  for (int k = 0; k < CH; ++k) {
    const int i = tid + k * TS;
    int w = 0;
    if (i < NALL) {
      ind[i] = 0;
      w = mword[(size_t)b * NALL + i];
    }
    ew[k] = w;
  }
  __syncthreads();
  #pragma unroll
  for (int k = 0; k < CH; ++k) {
    const int w = ew[k];
    if (w & 0x80) atomicAdd(&hist[w >> 9], (w & 0x100) ? 1 : (1 << 16));
  }
  __syncthreads();

  // ---- packed suffix scan, one bin per thread ----
  const int c = hist[tid];
  const int incl = block_incl_scan(c, tid, wsum);
  if (tid == TS - 1) s_total = incl;
  __syncthreads();
  const int total = s_total;

  #pragma unroll
  for (int p = 0; p < 2; ++p) {
    const int want = p ? KNEG : KPOS;
    const int sh = p ? 16 : 0;
    const int tot = (total >> sh) & 0xFFFF;
    if (tot >= want) {                              // !selall
      const int inc = (incl >> sh) & 0xFFFF;
      const int cp = (c >> sh) & 0xFFFF;
      const int above = tot - inc;                  // sum of bins > tid
      if (above < want && above + cp >= want) {     // unique boundary thread
        s_bstar[p] = tid; s_need[p] = want - above;
      }
    }
  }
  __syncthreads();

  const bool selall0 = ((total & 0xFFFF) < KPOS);
  const bool selall1 = (((total >> 16) & 0xFFFF) < KNEG);

  // ---- mark: bins above boundary selected; boundary bins collected ----
  #pragma unroll
  for (int k = 0; k < CH; ++k) {
    const int w = ew[k];
    if (w & 0x80) {
      const int i = tid + k * TS;
      const int p = (w & 0x100) ? 0 : 1;
      const bool selall = p ? selall1 : selall0;
      const int bin = w >> 9;
      if (selall || bin > s_bstar[p]) {
        ind[i] = 1;
      } else if (bin == s_bstar[p]) {
        int pos = atomicAdd(&bcnt[p], 1);
        if (pos < BCAP) {
          bval[p][pos] = noise[((size_t)b * NALL + i) * 2 + p];  // rare reload
          bidx_[p][pos] = i;
        }
      }
    }
  }
  __syncthreads();

  // ---- boundary-bin exact top-k via parallel rank (value desc, idx asc) ----
  #pragma unroll
  for (int p = 0; p < 2; ++p) {
    const bool selall = p ? selall1 : selall0;
    if (selall) continue;
    int cnt = bcnt[p]; if (cnt > BCAP) cnt = BCAP;
    const int need = s_need[p];
    for (int x = tid; x < cnt; x += TS) {
      const float v = bval[p][x];
      const int id = bidx_[p][x];
      int rank = 0;
      for (int y = 0; y < cnt; ++y) {
        const float vy = bval[p][y];
        const int iy2 = bidx_[p][y];
        rank += (vy > v) || (vy == v && iy2 < id);
      }
      if (rank < need) ind[id] = 1;
    }
  }
  __syncthreads();

  // ---- ordering: ones ascending then zeros ascending (top_k of 0/1) ----
  const int start = tid * CH;
  const int end = (start + CH < NALL) ? (start + CH) : NALL;
  int cnt1 = 0;
  for (int i = start; i < end; ++i) cnt1 += ind[i];
  const int incl1 = block_incl_scan(cnt1, tid, wsum);
  if (tid == TS - 1) s_total = incl1;
  __syncthreads();
  const int K1 = s_total;
  int ones_before = incl1 - cnt1;
  const int nzero = NSAMP - K1;
  for (int i = start; i < end; ++i) {
    if (ind[i]) {
      sorder[ones_before] = (unsigned short)i;
      ones_before++;
    } else {
      const int zrank = i - ones_before;
      if (zrank < nzero) sorder[K1 + zrank] = (unsigned short)i;
    }
  }
  __syncthreads();

  // ---- fused gather + encode + write (one sample per thread) ----
  if (tid < NSAMP) {
    const int s = tid;
    const int idx = sorder[s];
    const size_t t = (size_t)b * NSAMP + s;

    float4 A = (idx < NROIS)
      ? reinterpret_cast<const float4*>(rois)[(size_t)b * NROIS + idx]
      : reinterpret_cast<const float4*>(gt)[(size_t)b * NGT + (idx - NROIS)];

    const int w = mword[(size_t)b * NALL + idx];
    const int col = w & 0x7F;
    const bool pos = (((w >> 7) & 3) == 3);

    float e0 = 0.f, e1 = 0.f, e2 = 0.f, e3 = 0.f, cls = 0.f;
    if (pos) {
      float4 G = reinterpret_cast<const float4*>(gt)[(size_t)b * NGT + col];
      float ah = A.z - A.x, aw = A.w - A.y;
      float acy = A.x + 0.5f * ah, acx = A.y + 0.5f * aw;
      float bh = G.z - G.x, bw = G.w - G.y;
      float bcy = G.x + 0.5f * bh, bcx = G.y + 0.5f * bw;
      e0 = ((bcy - acy) / ah) / 0.1f;
      e1 = ((bcx - acx) / aw) / 0.1f;
      e2 = logf(bh / ah) / 0.2f;
      e3 = logf(bw / aw) / 0.2f;
      cls = gtcls[(size_t)b * NGT + col];
    }

    float* o_rois = out;                           // NB*NSAMP*4
    float* o_enc  = out + (size_t)NB * NSAMP * 4;  // NB*NSAMP*4
    float* o_bw   = out + (size_t)NB * NSAMP * 8;
    float* o_cls  = o_bw + (size_t)NB * NSAMP;
    float* o_cw   = o_cls + (size_t)NB * NSAMP;

    reinterpret_cast<float4*>(o_rois)[t] = A;
    float4 E; E.x = e0; E.y = e1; E.z = e2; E.w = e3;
    reinterpret_cast<float4*>(o_enc)[t] = E;
    o_bw[t]  = pos ? 1.0f : 0.0f;
    o_cls[t] = cls;
    o_cw[t]  = (s < K1) ? 1.0f : 0.0f;
  }
}

extern "C" void kernel_launch(void* const* d_in, const int* in_sizes, int n_in,
                              void* d_out, int out_size, void* d_ws, size_t ws_size,
                              hipStream_t stream) {
  const float* rois  = (const float*)d_in[0];
  const float* gt    = (const float*)d_in[1];
  const float* gtcls = (const float*)d_in[2];
  const float* noise = (const float*)d_in[3];
  float* out = (float*)d_out;

  uint8_t* ws = (uint8_t*)d_ws;
  int* mword  = (int*)ws;                                          // NB*NALL
  int* fllist = mword + (size_t)NB * NALL;                         // NB*NALL
  int* flcnt  = fllist + (size_t)NB * NALL;                        // NB

  hipMemsetAsync(flcnt, 0, NB * sizeof(int), stream);

  dim3 g1(NALL / 128, NB);  // (65, 32)
  k_match<<<g1, 128, 0, stream>>>(rois, gt, noise, mword, flcnt, fllist);
  dim3 g2((NALL + 255) / 256, NB);  // (33, 32) capacity; most blocks exit
  k_match2<<<g2, 256, 0, stream>>>(rois, gt, noise, flcnt, fllist, mword);
  k_select<<<NB, TS, 0, stream>>>(mword, noise, rois, gt, gtcls, out);
}

// Round 16
// 43.152 us; speedup vs baseline: 2.1329x; 2.1329x over previous
//
#include <hip/hip_runtime.h>
#include <cstdint>

#define NB 32
#define NROIS 8192
#define NGT 128
#define NALL (NROIS + NGT)   // 8320
#define NSAMP 512
#define KPOS 128
#define KNEG 384
#define BCAP 1024
#define TS 1024              // k_select threads (16 waves)
#define CH 9                 // ceil(NALL/TS)

// ---------------- Kernel 1: IoU matching (4-roi register tile × gt quadrant) --
// 256 thr/block, grid (33,32); block owns 256 rois. Thread (lane,q) evaluates
// rois {base+lane+64r, r=0..3} against gt quadrant [32q,32q+32): each gt's
// ds_read_b128 is amortized over 4 pairs and feeds 4 INDEPENDENT cross-mul
// argmax chains (ILP without extra LDS traffic). Wave count stays 4160
// (~16 waves/CU). Quadrant partials merge via LDS; wave q merges roi
// lane+64q == its own A[q] (no reload). Ordering identical to validated
// R9/R11: iou_j > iou_b <=> inter_j*uc_b > inter_b*uc_j (uc=max(uni,1e-8)),
// ascending j strict >, ascending-quadrant merge (lower j wins ties); ONE
// contract-off IEEE div on the winner gives bit-exact >=0.5/>=0.0 codes.
// Any masked [-1]*4 box -> block-uniform dense reference slow path.
__global__ __launch_bounds__(256) void k_match(
    const float* __restrict__ rois,   // B,NROIS,4
    const float* __restrict__ gt,     // B,NGT,4
    const float* __restrict__ noise,  // B,NALL,2
    int* __restrict__ mword)          // B*NALL : col | code<<7 | bin<<9
{
  __shared__ float4 sg[NGT];
  __shared__ float sab[NGT];           // areas (slow path only)
  __shared__ int s_any;
  __shared__ float pbi[4][64][4];      // [q][lane][r]
  __shared__ float pbu[4][64][4];
  __shared__ int   pbc[4][64][4];

  const int b = blockIdx.y;
  const int tid = threadIdx.x;
  const int lane = tid & 63;
  const int q = tid >> 6;
  const float4* gt4 = reinterpret_cast<const float4*>(gt) + (size_t)b * NGT;
  const float4* rois4 = reinterpret_cast<const float4*>(rois) + (size_t)b * NROIS;

  if (tid == 0) s_any = 0;
  bool mflag = false;
  if (tid < NGT) {
    float4 g0 = gt4[tid];
    sg[tid] = g0;
    sab[tid] = (g0.z - g0.x) * (g0.w - g0.y);
    mflag = (g0.x == -1.0f) && (g0.y == -1.0f) && (g0.z == -1.0f) && (g0.w == -1.0f);
  }
  __syncthreads();                      // sg staged + s_any init

  const int base = blockIdx.x * 256;
  float4 A[4];
  float aar[4];
  bool act[4];
  bool maAny = false;
  #pragma unroll
  for (int r = 0; r < 4; ++r) {
    const int idx = base + lane + 64 * r;
    act[r] = (idx < NALL);
    A[r] = act[r] ? ((idx < NROIS) ? rois4[idx] : sg[idx - NROIS]) : rois4[0];
    aar[r] = (A[r].z - A[r].x) * (A[r].w - A[r].y);
    maAny |= act[r] && (A[r].x == -1.0f) && (A[r].y == -1.0f) && (A[r].z == -1.0f) && (A[r].w == -1.0f);
  }
  if (mflag || maAny) atomicOr(&s_any, 1);
  __syncthreads();                      // s_any final (block-uniform)

  if (s_any == 0) {
    // ---- fast path: 4 roi-chains per thread over gt quadrant q ----
    float bi[4] = {0.f, 0.f, 0.f, 0.f};
    float bu[4] = {1.f, 1.f, 1.f, 1.f};
    int bc[4];
    #pragma unroll
    for (int r = 0; r < 4; ++r) bc[r] = 32 * q;   // quadrant's first j

    const float4* p = &sg[32 * q];
    #pragma unroll 8
    for (int jj = 0; jj < 32; ++jj) {
      const float4 g = p[jj];                      // one b128 for 4 pairs
      const float ab = (g.z - g.x) * (g.w - g.y);  // shared, VALU
      #pragma unroll
      for (int r = 0; r < 4; ++r) {
        float iy = fmaxf(fminf(A[r].z, g.z) - fmaxf(A[r].x, g.x), 0.0f);
        float ix = fmaxf(fminf(A[r].w, g.w) - fmaxf(A[r].y, g.y), 0.0f);
        float inter = iy * ix;
        float uc = fmaxf((aar[r] + ab) - inter, 1e-8f);
        const bool win = (inter * bu[r]) > (bi[r] * uc);
        bi[r] = win ? inter : bi[r];
        bu[r] = win ? uc : bu[r];
        bc[r] = win ? (32 * q + jj) : bc[r];       // ascending -> first-max
      }
    }
    #pragma unroll
    for (int r = 0; r < 4; ++r) {
      pbi[q][lane][r] = bi[r];
      pbu[q][lane][r] = bu[r];
      pbc[q][lane][r] = bc[r];
    }
    __syncthreads();

    // ---- merge: wave q owns roi base+lane+64q == this thread's A[q] ----
    const int idx = base + lane + 64 * q;
    if (idx < NALL) {
      float qi = pbi[0][lane][q], qu = pbu[0][lane][q];
      int qc = pbc[0][lane][q];
      #pragma unroll
      for (int qq = 1; qq < 4; ++qq) {             // ascending j; > keeps lower
        const float oi = pbi[qq][lane][q], ou = pbu[qq][lane][q];
        const int oc = pbc[qq][lane][q];
        const bool win = (oi * qu) > (qi * ou);
        qi = win ? oi : qi; qu = win ? ou : qu; qc = win ? oc : qc;
      }
      int code;
      {
        #pragma clang fp contract(off)
        const float4 g = sg[qc];
        float iy = fmaxf(fminf(A[q].z, g.z) - fmaxf(A[q].x, g.x), 0.0f);
        float ix = fmaxf(fminf(A[q].w, g.w) - fmaxf(A[q].y, g.y), 0.0f);
        float inter = iy * ix;
        float ab = (g.z - g.x) * (g.w - g.y);
        float uni = (aar[q] + ab) - inter;
        float bb = inter / fmaxf(uni, 1e-8f);      // IEEE-exact
        code = (bb >= 0.5f) ? 3 : ((bb >= 0.0f) ? 1 : 0);
      }
      float2 nz = reinterpret_cast<const float2*>(noise)[(size_t)b * NALL + idx];
      float v = (code == 3) ? nz.x : nz.y;
      int bin = (int)(v * 1024.0f);
      bin = bin < 0 ? 0 : (bin > 1023 ? 1023 : bin);
      mword[(size_t)b * NALL + idx] = qc | (code << 7) | (bin << 9);
    }
  } else {
    // ---- slow path (masked boxes; never taken for this data) ----
    const int idx = base + lane + 64 * q;
    if (idx < NALL) {
      #pragma clang fp contract(off)
      const float4 Aq = A[q];
      const float aq = aar[q];
      const bool ma = (Aq.x == -1.0f) && (Aq.y == -1.0f) && (Aq.z == -1.0f) && (Aq.w == -1.0f);
      float bb = -3.0e38f;
      int cc = 0;
      for (int j = 0; j < NGT; ++j) {
        float4 gg = sg[j];
        const bool mj = (gg.x == -1.0f) && (gg.y == -1.0f) && (gg.z == -1.0f) && (gg.w == -1.0f);
        float iy = fmaxf(fminf(Aq.z, gg.z) - fmaxf(Aq.x, gg.x), 0.0f);
        float ix = fmaxf(fminf(Aq.w, gg.w) - fmaxf(Aq.y, gg.y), 0.0f);
        float inter = iy * ix;
        float uni = (aq + sab[j]) - inter;
        float iou = inter / fmaxf(uni, 1e-8f);
        if (ma || mj) iou = -1.0f;
        if (iou > bb) { bb = iou; cc = j; }        // ascending strict > = first-max
      }
      int code = (bb >= 0.5f) ? 3 : ((bb >= 0.0f) ? 1 : 0);
      float2 nz = reinterpret_cast<const float2*>(noise)[(size_t)b * NALL + idx];
      float v = (code == 3) ? nz.x : nz.y;
      int bin = (int)(v * 1024.0f);
      bin = bin < 0 ? 0 : (bin > 1023 ? 1023 : bin);
      mword[(size_t)b * NALL + idx] = cc | (code << 7) | (bin << 9);
    }
  }
}

// ---------------- shfl-based block inclusive scan (TS=1024, 16 waves) -------
__device__ __forceinline__ int block_incl_scan(int v, int tid, int* wsum) {
  __syncthreads();  // protect wsum reuse across consecutive calls
  int s = v;
  #pragma unroll
  for (int off = 1; off < 64; off <<= 1) {
    int u = __shfl_up(s, off);
    if ((tid & 63) >= off) s += u;
  }
  const int wid = tid >> 6;
  if ((tid & 63) == 63) wsum[wid] = s;
  __syncthreads();
  if (wid == 0) {
    const int lane = tid & 63;
    int w = (lane < (TS >> 6)) ? wsum[lane] : 0;
    #pragma unroll
    for (int off = 1; off < (TS >> 6); off <<= 1) {
      int u = __shfl_up(w, off);
      if (lane >= off) w += u;
    }
    if (lane < (TS >> 6)) wsum[lane] = w;
  }
  __syncthreads();
  return s + (wid ? wsum[wid - 1] : 0);
}

// ---------------- Kernel 2: balanced sampling + ordering + gather ------------
__global__ __launch_bounds__(TS) void k_select(
    const int* __restrict__ mword,
    const float* __restrict__ noise,  // B,NALL,2
    const float* __restrict__ rois,
    const float* __restrict__ gt,
    const float* __restrict__ gtcls,  // B,NGT,1
    float* __restrict__ out)
{
  #pragma clang fp contract(off)
  const int b = blockIdx.x;
  const int tid = threadIdx.x;

  __shared__ int hist[1024];            // packed pos|neg<<16
  __shared__ int wsum[TS >> 6];
  __shared__ int s_total;               // packed totals
  __shared__ float bval[2][BCAP];
  __shared__ int bidx_[2][BCAP];
  __shared__ int bcnt[2];
  __shared__ int s_bstar[2], s_need[2];
  __shared__ unsigned char ind[NALL];
  __shared__ unsigned short sorder[NSAMP];

  int ew[CH];     // packed word; bit7 set => candidate

  hist[tid] = 0;
  if (tid < 2) bcnt[tid] = 0;

  // ---- pass 1: one int load per element; histogram + ind init ----
  #pragma unroll
  for (int k = 0; k < CH; ++k) {
    const int i = tid + k * TS;
    int w = 0;
    if (i < NALL) {
      ind[i] = 0;
      w = mword[(size_t)b * NALL + i];
    }
    ew[k] = w;
  }
  __syncthreads();
  #pragma unroll
  for (int k = 0; k < CH; ++k) {
    const int w = ew[k];
    if (w & 0x80) atomicAdd(&hist[w >> 9], (w & 0x100) ? 1 : (1 << 16));
  }
  __syncthreads();

  // ---- packed suffix scan, one bin per thread ----
  const int c = hist[tid];
  const int incl = block_incl_scan(c, tid, wsum);
  if (tid == TS - 1) s_total = incl;
  __syncthreads();
  const int total = s_total;

  #pragma unroll
  for (int p = 0; p < 2; ++p) {
    const int want = p ? KNEG : KPOS;
    const int sh = p ? 16 : 0;
    const int tot = (total >> sh) & 0xFFFF;
    if (tot >= want) {                              // !selall
      const int inc = (incl >> sh) & 0xFFFF;
      const int cp = (c >> sh) & 0xFFFF;
      const int above = tot - inc;                  // sum of bins > tid
      if (above < want && above + cp >= want) {     // unique boundary thread
        s_bstar[p] = tid; s_need[p] = want - above;
      }
    }
  }
  __syncthreads();

  const bool selall0 = ((total & 0xFFFF) < KPOS);
  const bool selall1 = (((total >> 16) & 0xFFFF) < KNEG);

  // ---- mark: bins above boundary selected; boundary bins collected ----
  #pragma unroll
  for (int k = 0; k < CH; ++k) {
    const int w = ew[k];
    if (w & 0x80) {
      const int i = tid + k * TS;
      const int p = (w & 0x100) ? 0 : 1;
      const bool selall = p ? selall1 : selall0;
      const int bin = w >> 9;
      if (selall || bin > s_bstar[p]) {
        ind[i] = 1;
      } else if (bin == s_bstar[p]) {
        int pos = atomicAdd(&bcnt[p], 1);
        if (pos < BCAP) {
          bval[p][pos] = noise[((size_t)b * NALL + i) * 2 + p];  // rare reload
          bidx_[p][pos] = i;
        }
      }
    }
  }
  __syncthreads();

  // ---- boundary-bin exact top-k via parallel rank (value desc, idx asc) ----
  #pragma unroll
  for (int p = 0; p < 2; ++p) {
    const bool selall = p ? selall1 : selall0;
    if (selall) continue;
    int cnt = bcnt[p]; if (cnt > BCAP) cnt = BCAP;
    const int need = s_need[p];
    for (int x = tid; x < cnt; x += TS) {
      const float v = bval[p][x];
      const int id = bidx_[p][x];
      int rank = 0;
      for (int y = 0; y < cnt; ++y) {
        const float vy = bval[p][y];
        const int iy2 = bidx_[p][y];
        rank += (vy > v) || (vy == v && iy2 < id);
      }
      if (rank < need) ind[id] = 1;
    }
  }
  __syncthreads();

  // ---- ordering: ones ascending then zeros ascending (top_k of 0/1) ----
  const int start = tid * CH;
  const int end = (start + CH < NALL) ? (start + CH) : NALL;
  int cnt1 = 0;
  for (int i = start; i < end; ++i) cnt1 += ind[i];
  const int incl1 = block_incl_scan(cnt1, tid, wsum);
  if (tid == TS - 1) s_total = incl1;
  __syncthreads();
  const int K1 = s_total;
  int ones_before = incl1 - cnt1;
  const int nzero = NSAMP - K1;
  for (int i = start; i < end; ++i) {
    if (ind[i]) {
      sorder[ones_before] = (unsigned short)i;
      ones_before++;
    } else {
      const int zrank = i - ones_before;
      if (zrank < nzero) sorder[K1 + zrank] = (unsigned short)i;
    }
  }
  __syncthreads();

  // ---- fused gather + encode + write (one sample per thread) ----
  if (tid < NSAMP) {
    const int s = tid;
    const int idx = sorder[s];
    const size_t t = (size_t)b * NSAMP + s;

    float4 A = (idx < NROIS)
      ? reinterpret_cast<const float4*>(rois)[(size_t)b * NROIS + idx]
      : reinterpret_cast<const float4*>(gt)[(size_t)b * NGT + (idx - NROIS)];

    const int w = mword[(size_t)b * NALL + idx];
    const int col = w & 0x7F;
    const bool pos = (((w >> 7) & 3) == 3);

    float e0 = 0.f, e1 = 0.f, e2 = 0.f, e3 = 0.f, cls = 0.f;
    if (pos) {
      float4 G = reinterpret_cast<const float4*>(gt)[(size_t)b * NGT + col];
      float ah = A.z - A.x, aw = A.w - A.y;
      float acy = A.x + 0.5f * ah, acx = A.y + 0.5f * aw;
      float bh = G.z - G.x, bw = G.w - G.y;
      float bcy = G.x + 0.5f * bh, bcx = G.y + 0.5f * bw;
      e0 = ((bcy - acy) / ah) / 0.1f;
      e1 = ((bcx - acx) / aw) / 0.1f;
      e2 = logf(bh / ah) / 0.2f;
      e3 = logf(bw / aw) / 0.2f;
      cls = gtcls[(size_t)b * NGT + col];
    }

    float* o_rois = out;                           // NB*NSAMP*4
    float* o_enc  = out + (size_t)NB * NSAMP * 4;  // NB*NSAMP*4
    float* o_bw   = out + (size_t)NB * NSAMP * 8;
    float* o_cls  = o_bw + (size_t)NB * NSAMP;
    float* o_cw   = o_cls + (size_t)NB * NSAMP;

    reinterpret_cast<float4*>(o_rois)[t] = A;
    float4 E; E.x = e0; E.y = e1; E.z = e2; E.w = e3;
    reinterpret_cast<float4*>(o_enc)[t] = E;
    o_bw[t]  = pos ? 1.0f : 0.0f;
    o_cls[t] = cls;
    o_cw[t]  = (s < K1) ? 1.0f : 0.0f;
  }
}

extern "C" void kernel_launch(void* const* d_in, const int* in_sizes, int n_in,
                              void* d_out, int out_size, void* d_ws, size_t ws_size,
                              hipStream_t stream) {
  const float* rois  = (const float*)d_in[0];
  const float* gt    = (const float*)d_in[1];
  const float* gtcls = (const float*)d_in[2];
  const float* noise = (const float*)d_in[3];
  float* out = (float*)d_out;

  int* mword = (int*)d_ws;  // NB*NALL ints

  dim3 g1((NALL + 255) / 256, NB);  // (33, 32); 256 rois per block
  k_match<<<g1, 256, 0, stream>>>(rois, gt, noise, mword);
  k_select<<<NB, TS, 0, stream>>>(mword, noise, rois, gt, gtcls, out);
}